// Round 1
// baseline (3131.109 us; speedup 1.0000x reference)
//
#include <hip/hip_runtime.h>

typedef _Float16 f16;
typedef _Float16 f16x8 __attribute__((ext_vector_type(8)));
typedef float    f32x4 __attribute__((ext_vector_type(4)));

#define NSTEP 2048
#define HID   512
#define BATCH 32
#define SEQL  2048

// ---------------------------------------------------------------------------
// Phase 1: xproj[m][n] = sum_k x[m][k] * Wxh[n][k] + (bxh+bhh+bh)[n], f16 out
// M=65536, N=512, K=512.  Block: 64 rows x 512 cols, 256 threads (4 waves).
// ---------------------------------------------------------------------------
#define P1_AS 40   // padded lds stride (f16) to spread banks; 80B = 16B-aligned

__global__ __launch_bounds__(256, 2) void xproj_kernel(
    const float* __restrict__ x, const float* __restrict__ Wxh,
    const float* __restrict__ bxh, const float* __restrict__ bhh,
    const float* __restrict__ bh, f16* __restrict__ xp)
{
    __shared__ __align__(16) f16 As[64 * P1_AS];
    __shared__ __align__(16) f16 Bs[512 * P1_AS];

    const int t = threadIdx.x;
    const int wave = t >> 6, lane = t & 63;
    const size_t mbase = (size_t)blockIdx.x * 64;

    f32x4 acc[4][8];
#pragma unroll
    for (int i = 0; i < 4; i++)
#pragma unroll
        for (int j = 0; j < 8; j++) acc[i][j] = (f32x4){0.f, 0.f, 0.f, 0.f};

    const int r_st = t >> 2;          // 0..63
    const int koff = (t & 3) * 8;     // 0,8,16,24

    for (int k0 = 0; k0 < 512; k0 += 32) {
        __syncthreads();
        // stage A: 64 rows x 32 k (f32 -> f16)
        {
            const float* src = x + (mbase + r_st) * 512 + k0 + koff;
            float4 a0 = *(const float4*)src;
            float4 a1 = *(const float4*)(src + 4);
            f16x8 h;
            h[0] = (f16)a0.x; h[1] = (f16)a0.y; h[2] = (f16)a0.z; h[3] = (f16)a0.w;
            h[4] = (f16)a1.x; h[5] = (f16)a1.y; h[6] = (f16)a1.z; h[7] = (f16)a1.w;
            *(f16x8*)&As[r_st * P1_AS + koff] = h;
        }
        // stage B: 512 rows(n) x 32 k, 8 passes
#pragma unroll
        for (int i = 0; i < 8; i++) {
            int n = r_st + i * 64;
            const float* src = Wxh + (size_t)n * 512 + k0 + koff;
            float4 b0 = *(const float4*)src;
            float4 b1 = *(const float4*)(src + 4);
            f16x8 h;
            h[0] = (f16)b0.x; h[1] = (f16)b0.y; h[2] = (f16)b0.z; h[3] = (f16)b0.w;
            h[4] = (f16)b1.x; h[5] = (f16)b1.y; h[6] = (f16)b1.z; h[7] = (f16)b1.w;
            *(f16x8*)&Bs[n * P1_AS + koff] = h;
        }
        __syncthreads();

        // A frags: row = rt*16 + (lane&15), k = (lane>>4)*8 + j
        f16x8 af[4];
#pragma unroll
        for (int rt = 0; rt < 4; rt++)
            af[rt] = *(const f16x8*)&As[(rt * 16 + (lane & 15)) * P1_AS + (lane >> 4) * 8];
#pragma unroll
        for (int ct = 0; ct < 8; ct++) {
            f16x8 bf = *(const f16x8*)&Bs[((wave * 8 + ct) * 16 + (lane & 15)) * P1_AS + (lane >> 4) * 8];
#pragma unroll
            for (int rt = 0; rt < 4; rt++)
                acc[rt][ct] = __builtin_amdgcn_mfma_f32_16x16x32_f16(af[rt], bf, acc[rt][ct], 0, 0, 0);
        }
    }

    // epilogue: D col = lane&15, row = (lane>>4)*4 + r
#pragma unroll
    for (int ct = 0; ct < 8; ct++) {
        int n = wave * 128 + ct * 16 + (lane & 15);
        float bias = bxh[n] + bhh[n] + bh[n];
#pragma unroll
        for (int rt = 0; rt < 4; rt++) {
#pragma unroll
            for (int r = 0; r < 4; r++) {
                size_t m = mbase + rt * 16 + (lane >> 4) * 4 + r;
                xp[m * 512 + n] = (f16)(acc[rt][ct][r] + bias);
            }
        }
    }
}

// ---------------------------------------------------------------------------
// Phase 2: recurrence.  1 block (512 thr, 8 waves) per batch, 32 blocks.
// W_hh (f16, B-fragment layout) resident: 3 N-tiles/wave in VGPRs (192 regs),
// 1 N-tile/wave in LDS (128 KiB).  h double-buffered in LDS.
//
// Round 1 change: kill the per-step vmcnt(0) stalls.
//  (a) xp prefetch distance 2, rotating RAW f16 regs (cvt deferred to use) --
//      the wait at use becomes a counted vmcnt with ~2 steps of slack.
//  (b) raw s_barrier + manual lgkmcnt(0) instead of __syncthreads(): LDS
//      writes are made visible WITHOUT draining the global prefetch queue
//      (8-phase-template pattern; __syncthreads emits vmcnt(0) before
//      s_barrier and exposes full HBM latency every step).
// ---------------------------------------------------------------------------
#define P2_LDS_BYTES (2 * HID * 2 + 8 * 16 * 64 * 16)  // h bufs + ldsB = 133120

__global__ __launch_bounds__(512, 2) void rnn_kernel(
    const float* __restrict__ Whh, const f16* __restrict__ xp,
    f16* __restrict__ hfin)
{
    extern __shared__ __align__(16) char smem[];
    f16* hbuf0 = (f16*)smem;                 // 512
    f16* hbuf1 = hbuf0 + HID;                // 512
    f16* ldsB  = hbuf1 + HID;                // [(wave*16+kf)*64 + lane]*8 f16

    const int t = threadIdx.x;
    const int wave = t >> 6, lane = t & 63;
    const int b = blockIdx.x;

    const int c_in = lane & 15;              // fragment column
    const int k8   = (lane >> 4) * 8;        // fragment k base

    // ---- load W_hh fragments (one-time): tile nt = wave*4 + r ----
    f16x8 wreg[48];                          // 3 tiles x 16 kf -> 192 VGPRs
#pragma unroll
    for (int r = 0; r < 3; r++) {
        const float* wrow = Whh + (size_t)((wave * 4 + r) * 16 + c_in) * 512;
#pragma unroll
        for (int kf = 0; kf < 16; kf++) {
            float4 w0 = *(const float4*)(wrow + kf * 32 + k8);
            float4 w1 = *(const float4*)(wrow + kf * 32 + k8 + 4);
            f16x8 h;
            h[0] = (f16)w0.x; h[1] = (f16)w0.y; h[2] = (f16)w0.z; h[3] = (f16)w0.w;
            h[4] = (f16)w1.x; h[5] = (f16)w1.y; h[6] = (f16)w1.z; h[7] = (f16)w1.w;
            wreg[r * 16 + kf] = h;
        }
    }
    {   // 4th tile -> LDS in fragment order
        const float* wrow = Whh + (size_t)((wave * 4 + 3) * 16 + c_in) * 512;
#pragma unroll
        for (int kf = 0; kf < 16; kf++) {
            float4 w0 = *(const float4*)(wrow + kf * 32 + k8);
            float4 w1 = *(const float4*)(wrow + kf * 32 + k8 + 4);
            f16x8 h;
            h[0] = (f16)w0.x; h[1] = (f16)w0.y; h[2] = (f16)w0.z; h[3] = (f16)w0.w;
            h[4] = (f16)w1.x; h[5] = (f16)w1.y; h[6] = (f16)w1.z; h[7] = (f16)w1.w;
            *(f16x8*)&ldsB[(size_t)wave * 8192 + kf * 512 + lane * 8] = h;
        }
    }
    hbuf0[t & (HID - 1)] = (f16)0.f;         // h0 = 0 (512 threads cover 512)
    __syncthreads();

    const f16* xprow = xp + (size_t)b * SEQL * 512 + wave * 64 + lane;
    const int ldsb_base = wave * 8192 + lane * 8;

    // prefetch pipeline: raw f16, distance 2 (cvt deferred to use point)
    f16 xr0 = xprow[0];
    f16 xr1 = xprow[512];
    for (int s = 0; s < NSTEP; s++) {
        const f16* cur = (s & 1) ? hbuf1 : hbuf0;
        f16*       nxt = (s & 1) ? hbuf0 : hbuf1;
        int sn = s + 2; if (sn > NSTEP - 1) sn = NSTEP - 1;
        f16 xr2 = xprow[(size_t)sn * 512];   // stays in flight ~2 steps

        f32x4 a0 = (f32x4){0.f,0.f,0.f,0.f}, a1 = a0, a2 = a0, a3 = a0;
#pragma unroll
        for (int kf = 0; kf < 16; kf++) {
            // A broadcast frag: every "row" of A is h -> addr indep of lane&15
            f16x8 av = *(const f16x8*)&cur[kf * 32 + k8];
            a0 = __builtin_amdgcn_mfma_f32_16x16x32_f16(av, wreg[kf],      a0, 0, 0, 0);
            a1 = __builtin_amdgcn_mfma_f32_16x16x32_f16(av, wreg[16 + kf], a1, 0, 0, 0);
            a2 = __builtin_amdgcn_mfma_f32_16x16x32_f16(av, wreg[32 + kf], a2, 0, 0, 0);
            f16x8 bl = *(const f16x8*)&ldsB[ldsb_base + kf * 512];
            a3 = __builtin_amdgcn_mfma_f32_16x16x32_f16(av, bl, a3, 0, 0, 0);
        }
        // lane l owns h_new[wave*64 + l]: tile = l>>4, col = l&15, any row (reg 0)
        int r = lane >> 4;
        float v = (r == 0) ? a0[0] : (r == 1) ? a1[0] : (r == 2) ? a2[0] : a3[0];
        v += (float)xr0;                     // counted vmcnt wait, ~2 steps slack
        // tanh(v) = 1 - 2/(exp(2v)+1)   (saturates correctly, no NaN)
        float e = __expf(2.f * v);
        v = 1.f - 2.f / (e + 1.f);
        nxt[wave * 64 + lane] = (f16)v;
        xr0 = xr1; xr1 = xr2;
        // LDS-only fence + raw barrier: global prefetch stays in flight.
        asm volatile("s_waitcnt lgkmcnt(0)" ::: "memory");
        __builtin_amdgcn_s_barrier();
        asm volatile("" ::: "memory");
    }
    // NSTEP even -> final h sits in hbuf0
    hfin[(size_t)b * 512 + t] = hbuf0[t & (HID - 1)];
}

// ---------------------------------------------------------------------------
// Phase 3: out[b][o] = sum_k h[b][k] * Wfc[o][k] + bfc[o]  (fp32 out)
// 32 blocks x 16 o-slice, 256 threads; h staged in padded LDS.
// ---------------------------------------------------------------------------
#define P3_HS 520  // padded stride (f16); 1040B is 16B-aligned

__global__ __launch_bounds__(256, 2) void fc_kernel(
    const f16* __restrict__ hfin, const float* __restrict__ Wfc,
    const float* __restrict__ bfc, float* __restrict__ out)
{
    __shared__ __align__(16) f16 hs[BATCH * P3_HS];
    const int t = threadIdx.x;
    // stage h (coalesced 2B loads, scattered padded LDS writes — one-time)
    for (int i = 0; i < 64; i++) {
        int e = i * 256 + t;                 // 0..16383
        hs[(e >> 9) * P3_HS + (e & 511)] = hfin[e];
    }
    __syncthreads();

    const int bidx = t & 31;
    const int oi = t >> 5;                   // 0..7
    const int o0 = blockIdx.x * 16;
    const int oA = o0 + oi, oB = o0 + oi + 8;
    const float* wA = Wfc + (size_t)oA * 512;
    const float* wB = Wfc + (size_t)oB * 512;

    float sA = 0.f, sB = 0.f;
#pragma unroll 4
    for (int kb = 0; kb < 64; kb++) {
        f16x8 hv = *(const f16x8*)&hs[bidx * P3_HS + kb * 8];
        float4 wa0 = *(const float4*)(wA + kb * 8);
        float4 wa1 = *(const float4*)(wA + kb * 8 + 4);
        float4 wb0 = *(const float4*)(wB + kb * 8);
        float4 wb1 = *(const float4*)(wB + kb * 8 + 4);
        float h0 = (float)hv[0], h1 = (float)hv[1], h2 = (float)hv[2], h3 = (float)hv[3];
        float h4 = (float)hv[4], h5 = (float)hv[5], h6 = (float)hv[6], h7 = (float)hv[7];
        sA += wa0.x*h0 + wa0.y*h1 + wa0.z*h2 + wa0.w*h3 + wa1.x*h4 + wa1.y*h5 + wa1.z*h6 + wa1.w*h7;
        sB += wb0.x*h0 + wb0.y*h1 + wb0.z*h2 + wb0.w*h3 + wb1.x*h4 + wb1.y*h5 + wb1.z*h6 + wb1.w*h7;
    }
    out[(size_t)bidx * 512 + oA] = sA + bfc[oA];
    out[(size_t)bidx * 512 + oB] = sB + bfc[oB];
}

// ---------------------------------------------------------------------------
extern "C" void kernel_launch(void* const* d_in, const int* in_sizes, int n_in,
                              void* d_out, int out_size, void* d_ws, size_t ws_size,
                              hipStream_t stream) {
    const float* x    = (const float*)d_in[0];
    const float* Wxh  = (const float*)d_in[1];
    const float* bxh  = (const float*)d_in[2];
    const float* Whh  = (const float*)d_in[3];
    const float* bhh  = (const float*)d_in[4];
    const float* bh   = (const float*)d_in[5];
    const float* Wfc  = (const float*)d_in[6];
    const float* bfc  = (const float*)d_in[7];
    float* outp = (float*)d_out;

    f16* xp   = (f16*)d_ws;                                   // 64 MiB
    f16* hfin = (f16*)((char*)d_ws + (size_t)BATCH * SEQL * 512 * 2);

    // allow 130 KiB dynamic LDS for the rnn kernel (idempotent, capture-safe)
    hipFuncSetAttribute((const void*)rnn_kernel,
                        hipFuncAttributeMaxDynamicSharedMemorySize, 160 * 1024);

    xproj_kernel<<<(BATCH * SEQL) / 64, 256, 0, stream>>>(x, Wxh, bxh, bhh, bh, xp);
    rnn_kernel<<<BATCH, 512, P2_LDS_BYTES, stream>>>(Whh, xp, hfin);
    fc_kernel<<<32, 256, 0, stream>>>(hfin, Wfc, bfc, outp);
}

// Round 2
// 3073.540 us; speedup vs baseline: 1.0187x; 1.0187x over previous
//
#include <hip/hip_runtime.h>

typedef _Float16 f16;
typedef _Float16 f16x8 __attribute__((ext_vector_type(8)));
typedef float    f32x4 __attribute__((ext_vector_type(4)));

#define NSTEP 2048
#define HID   512
#define BATCH 32
#define SEQL  2048

// ---------------------------------------------------------------------------
// Phase 1: xproj[m][n] = sum_k x[m][k] * Wxh[n][k] + (bxh+bhh+bh)[n], f16 out
// M=65536, N=512, K=512.  Block: 64 rows x 512 cols, 256 threads (4 waves).
// ---------------------------------------------------------------------------
#define P1_AS 40   // padded lds stride (f16) to spread banks; 80B = 16B-aligned

__global__ __launch_bounds__(256, 2) void xproj_kernel(
    const float* __restrict__ x, const float* __restrict__ Wxh,
    const float* __restrict__ bxh, const float* __restrict__ bhh,
    const float* __restrict__ bh, f16* __restrict__ xp)
{
    __shared__ __align__(16) f16 As[64 * P1_AS];
    __shared__ __align__(16) f16 Bs[512 * P1_AS];

    const int t = threadIdx.x;
    const int wave = t >> 6, lane = t & 63;
    const size_t mbase = (size_t)blockIdx.x * 64;

    f32x4 acc[4][8];
#pragma unroll
    for (int i = 0; i < 4; i++)
#pragma unroll
        for (int j = 0; j < 8; j++) acc[i][j] = (f32x4){0.f, 0.f, 0.f, 0.f};

    const int r_st = t >> 2;          // 0..63
    const int koff = (t & 3) * 8;     // 0,8,16,24

    for (int k0 = 0; k0 < 512; k0 += 32) {
        __syncthreads();
        // stage A: 64 rows x 32 k (f32 -> f16)
        {
            const float* src = x + (mbase + r_st) * 512 + k0 + koff;
            float4 a0 = *(const float4*)src;
            float4 a1 = *(const float4*)(src + 4);
            f16x8 h;
            h[0] = (f16)a0.x; h[1] = (f16)a0.y; h[2] = (f16)a0.z; h[3] = (f16)a0.w;
            h[4] = (f16)a1.x; h[5] = (f16)a1.y; h[6] = (f16)a1.z; h[7] = (f16)a1.w;
            *(f16x8*)&As[r_st * P1_AS + koff] = h;
        }
        // stage B: 512 rows(n) x 32 k, 8 passes
#pragma unroll
        for (int i = 0; i < 8; i++) {
            int n = r_st + i * 64;
            const float* src = Wxh + (size_t)n * 512 + k0 + koff;
            float4 b0 = *(const float4*)src;
            float4 b1 = *(const float4*)(src + 4);
            f16x8 h;
            h[0] = (f16)b0.x; h[1] = (f16)b0.y; h[2] = (f16)b0.z; h[3] = (f16)b0.w;
            h[4] = (f16)b1.x; h[5] = (f16)b1.y; h[6] = (f16)b1.z; h[7] = (f16)b1.w;
            *(f16x8*)&Bs[n * P1_AS + koff] = h;
        }
        __syncthreads();

        // A frags: row = rt*16 + (lane&15), k = (lane>>4)*8 + j
        f16x8 af[4];
#pragma unroll
        for (int rt = 0; rt < 4; rt++)
            af[rt] = *(const f16x8*)&As[(rt * 16 + (lane & 15)) * P1_AS + (lane >> 4) * 8];
#pragma unroll
        for (int ct = 0; ct < 8; ct++) {
            f16x8 bf = *(const f16x8*)&Bs[((wave * 8 + ct) * 16 + (lane & 15)) * P1_AS + (lane >> 4) * 8];
#pragma unroll
            for (int rt = 0; rt < 4; rt++)
                acc[rt][ct] = __builtin_amdgcn_mfma_f32_16x16x32_f16(af[rt], bf, acc[rt][ct], 0, 0, 0);
        }
    }

    // epilogue: D col = lane&15, row = (lane>>4)*4 + r
#pragma unroll
    for (int ct = 0; ct < 8; ct++) {
        int n = wave * 128 + ct * 16 + (lane & 15);
        float bias = bxh[n] + bhh[n] + bh[n];
#pragma unroll
        for (int rt = 0; rt < 4; rt++) {
#pragma unroll
            for (int r = 0; r < 4; r++) {
                size_t m = mbase + rt * 16 + (lane >> 4) * 4 + r;
                xp[m * 512 + n] = (f16)(acc[rt][ct][r] + bias);
            }
        }
    }
}

// ---------------------------------------------------------------------------
// Phase 2: recurrence.  1 block (512 thr, 8 waves) per batch, 32 blocks.
// Step cost model (per CU): MFMA issue ~620 cyc (overlaps), LDS ds_read_b128
// stream of the LDS-resident W_hh fraction is the serial bottleneck
// (~85 B/cyc on one LDS unit).  r0 kept 16/64 kf-frags in LDS = 128 KB/step
// ~ 1540 cyc.  Round 2: 52/64 frags in registers (208 regs + 16 acc + ~30
// misc fits the 256-reg budget at 2 waves/SIMD), only 12 kf in LDS
// = 96 KB/step.  Barrier reverted to __syncthreads() (r1 asm barriers
// blocked compiler scheduling and regressed -334 us).
// ---------------------------------------------------------------------------
#define P2_LDS_BYTES (2 * HID * 2 + 8 * 12 * 512 * 2)  // h bufs + ldsB = 100352

__global__ __launch_bounds__(512, 2) void rnn_kernel(
    const float* __restrict__ Whh, const f16* __restrict__ xp,
    f16* __restrict__ hfin)
{
    extern __shared__ __align__(16) char smem[];
    f16* hbuf0 = (f16*)smem;                 // 512
    f16* hbuf1 = hbuf0 + HID;                // 512
    f16* ldsB  = hbuf1 + HID;                // [(wave*12 + (kf-4))*512 + lane*8]

    const int t = threadIdx.x;
    const int wave = t >> 6, lane = t & 63;
    const int b = blockIdx.x;

    const int c_in = lane & 15;              // fragment column
    const int k8   = (lane >> 4) * 8;        // fragment k base

    // ---- load W_hh fragments (one-time) ----
    // tiles nt = wave*4 + r, r=0..2 fully in reg; tile 3: kf 0..3 in reg,
    // kf 4..15 in LDS (fragment order).
    f16x8 wreg[52];                          // 52 frags -> 208 regs
#pragma unroll
    for (int r = 0; r < 3; r++) {
        const float* wrow = Whh + (size_t)((wave * 4 + r) * 16 + c_in) * 512;
#pragma unroll
        for (int kf = 0; kf < 16; kf++) {
            float4 w0 = *(const float4*)(wrow + kf * 32 + k8);
            float4 w1 = *(const float4*)(wrow + kf * 32 + k8 + 4);
            f16x8 h;
            h[0] = (f16)w0.x; h[1] = (f16)w0.y; h[2] = (f16)w0.z; h[3] = (f16)w0.w;
            h[4] = (f16)w1.x; h[5] = (f16)w1.y; h[6] = (f16)w1.z; h[7] = (f16)w1.w;
            wreg[r * 16 + kf] = h;
        }
    }
    {   // 4th tile
        const float* wrow = Whh + (size_t)((wave * 4 + 3) * 16 + c_in) * 512;
#pragma unroll
        for (int kf = 0; kf < 16; kf++) {
            float4 w0 = *(const float4*)(wrow + kf * 32 + k8);
            float4 w1 = *(const float4*)(wrow + kf * 32 + k8 + 4);
            f16x8 h;
            h[0] = (f16)w0.x; h[1] = (f16)w0.y; h[2] = (f16)w0.z; h[3] = (f16)w0.w;
            h[4] = (f16)w1.x; h[5] = (f16)w1.y; h[6] = (f16)w1.z; h[7] = (f16)w1.w;
            if (kf < 4)
                wreg[48 + kf] = h;
            else
                *(f16x8*)&ldsB[((size_t)wave * 12 + (kf - 4)) * 512 + lane * 8] = h;
        }
    }
    hbuf0[t & (HID - 1)] = (f16)0.f;         // h0 = 0 (512 threads cover 512)
    __syncthreads();

    const f16* xprow = xp + (size_t)b * SEQL * 512 + wave * 64 + lane;
    const int ldsb_base = wave * 12 * 512 + lane * 8;

    // xp prefetch: raw f16, distance 2; cvt deferred to use point.  The
    // __syncthreads() vmcnt drain at step end is ~1500+ cyc after issue,
    // so the HBM latency is fully hidden.
    f16 xr0 = xprow[0];
    f16 xr1 = xprow[512];
    for (int s = 0; s < NSTEP; s++) {
        const f16* cur = (s & 1) ? hbuf1 : hbuf0;
        f16*       nxt = (s & 1) ? hbuf0 : hbuf1;
        int sn = s + 2; if (sn > NSTEP - 1) sn = NSTEP - 1;
        f16 xr2 = xprow[(size_t)sn * 512];

        f32x4 a0 = (f32x4){0.f,0.f,0.f,0.f}, a1 = a0, a2 = a0, a3 = a0;
        // kf 0..3: tile-3 frag from registers
#pragma unroll
        for (int kf = 0; kf < 4; kf++) {
            f16x8 av = *(const f16x8*)&cur[kf * 32 + k8];   // broadcast (4 uniq addrs)
            a0 = __builtin_amdgcn_mfma_f32_16x16x32_f16(av, wreg[kf],      a0, 0, 0, 0);
            a1 = __builtin_amdgcn_mfma_f32_16x16x32_f16(av, wreg[16 + kf], a1, 0, 0, 0);
            a2 = __builtin_amdgcn_mfma_f32_16x16x32_f16(av, wreg[32 + kf], a2, 0, 0, 0);
            a3 = __builtin_amdgcn_mfma_f32_16x16x32_f16(av, wreg[48 + kf], a3, 0, 0, 0);
        }
        // kf 4..15: tile-3 frag streamed from LDS (12 x ds_read_b128 / wave)
#pragma unroll
        for (int kf = 4; kf < 16; kf++) {
            f16x8 av = *(const f16x8*)&cur[kf * 32 + k8];
            a0 = __builtin_amdgcn_mfma_f32_16x16x32_f16(av, wreg[kf],      a0, 0, 0, 0);
            a1 = __builtin_amdgcn_mfma_f32_16x16x32_f16(av, wreg[16 + kf], a1, 0, 0, 0);
            a2 = __builtin_amdgcn_mfma_f32_16x16x32_f16(av, wreg[32 + kf], a2, 0, 0, 0);
            f16x8 bl = *(const f16x8*)&ldsB[ldsb_base + (kf - 4) * 512];
            a3 = __builtin_amdgcn_mfma_f32_16x16x32_f16(av, bl, a3, 0, 0, 0);
        }
        // lane l owns h_new[wave*64 + l]: tile = l>>4, col = l&15, any row (reg 0)
        int r = lane >> 4;
        float v = (r == 0) ? a0[0] : (r == 1) ? a1[0] : (r == 2) ? a2[0] : a3[0];
        v += (float)xr0;
        // tanh(v) = 1 - 2/(exp(2v)+1)   (saturates correctly, no NaN)
        float e = __expf(2.f * v);
        v = 1.f - 2.f / (e + 1.f);
        nxt[wave * 64 + lane] = (f16)v;
        xr0 = xr1; xr1 = xr2;
        __syncthreads();
    }
    // NSTEP even -> final h sits in hbuf0
    hfin[(size_t)b * 512 + t] = hbuf0[t & (HID - 1)];
}

// ---------------------------------------------------------------------------
// Phase 3: out[b][o] = sum_k h[b][k] * Wfc[o][k] + bfc[o]  (fp32 out)
// 32 blocks x 16 o-slice, 256 threads; h staged in padded LDS.
// ---------------------------------------------------------------------------
#define P3_HS 520  // padded stride (f16); 1040B is 16B-aligned

__global__ __launch_bounds__(256, 2) void fc_kernel(
    const f16* __restrict__ hfin, const float* __restrict__ Wfc,
    const float* __restrict__ bfc, float* __restrict__ out)
{
    __shared__ __align__(16) f16 hs[BATCH * P3_HS];
    const int t = threadIdx.x;
    // stage h (coalesced 2B loads, scattered padded LDS writes — one-time)
    for (int i = 0; i < 64; i++) {
        int e = i * 256 + t;                 // 0..16383
        hs[(e >> 9) * P3_HS + (e & 511)] = hfin[e];
    }
    __syncthreads();

    const int bidx = t & 31;
    const int oi = t >> 5;                   // 0..7
    const int o0 = blockIdx.x * 16;
    const int oA = o0 + oi, oB = o0 + oi + 8;
    const float* wA = Wfc + (size_t)oA * 512;
    const float* wB = Wfc + (size_t)oB * 512;

    float sA = 0.f, sB = 0.f;
#pragma unroll 4
    for (int kb = 0; kb < 64; kb++) {
        f16x8 hv = *(const f16x8*)&hs[bidx * P3_HS + kb * 8];
        float4 wa0 = *(const float4*)(wA + kb * 8);
        float4 wa1 = *(const float4*)(wA + kb * 8 + 4);
        float4 wb0 = *(const float4*)(wB + kb * 8);
        float4 wb1 = *(const float4*)(wB + kb * 8 + 4);
        float h0 = (float)hv[0], h1 = (float)hv[1], h2 = (float)hv[2], h3 = (float)hv[3];
        float h4 = (float)hv[4], h5 = (float)hv[5], h6 = (float)hv[6], h7 = (float)hv[7];
        sA += wa0.x*h0 + wa0.y*h1 + wa0.z*h2 + wa0.w*h3 + wa1.x*h4 + wa1.y*h5 + wa1.z*h6 + wa1.w*h7;
        sB += wb0.x*h0 + wb0.y*h1 + wb0.z*h2 + wb0.w*h3 + wb1.x*h4 + wb1.y*h5 + wb1.z*h6 + wb1.w*h7;
    }
    out[(size_t)bidx * 512 + oA] = sA + bfc[oA];
    out[(size_t)bidx * 512 + oB] = sB + bfc[oB];
}

// ---------------------------------------------------------------------------
extern "C" void kernel_launch(void* const* d_in, const int* in_sizes, int n_in,
                              void* d_out, int out_size, void* d_ws, size_t ws_size,
                              hipStream_t stream) {
    const float* x    = (const float*)d_in[0];
    const float* Wxh  = (const float*)d_in[1];
    const float* bxh  = (const float*)d_in[2];
    const float* Whh  = (const float*)d_in[3];
    const float* bhh  = (const float*)d_in[4];
    const float* bh   = (const float*)d_in[5];
    const float* Wfc  = (const float*)d_in[6];
    const float* bfc  = (const float*)d_in[7];
    float* outp = (float*)d_out;

    f16* xp   = (f16*)d_ws;                                   // 64 MiB
    f16* hfin = (f16*)((char*)d_ws + (size_t)BATCH * SEQL * 512 * 2);

    // allow 100 KiB dynamic LDS for the rnn kernel (idempotent, capture-safe)
    hipFuncSetAttribute((const void*)rnn_kernel,
                        hipFuncAttributeMaxDynamicSharedMemorySize, 160 * 1024);

    xproj_kernel<<<(BATCH * SEQL) / 64, 256, 0, stream>>>(x, Wxh, bxh, bhh, bh, xp);
    rnn_kernel<<<BATCH, 512, P2_LDS_BYTES, stream>>>(Whh, xp, hfin);
    fc_kernel<<<32, 256, 0, stream>>>(hfin, Wfc, bfc, outp);
}

// Round 3
// 3023.539 us; speedup vs baseline: 1.0356x; 1.0165x over previous
//
#include <hip/hip_runtime.h>

typedef _Float16 f16;
typedef _Float16 f16x8 __attribute__((ext_vector_type(8)));
typedef float    f32x4 __attribute__((ext_vector_type(4)));

#define NSTEP 2048
#define HID   512
#define BATCH 32
#define SEQL  2048

// ---------------------------------------------------------------------------
// Phase 1: xproj[m][n] = sum_k x[m][k] * Wxh[n][k] + (bxh+bhh+bh)[n], f16 out
// M=65536, N=512, K=512.  Block: 64 rows x 512 cols, 256 threads (4 waves).
// ---------------------------------------------------------------------------
#define P1_AS 40   // padded lds stride (f16) to spread banks; 80B = 16B-aligned

__global__ __launch_bounds__(256, 2) void xproj_kernel(
    const float* __restrict__ x, const float* __restrict__ Wxh,
    const float* __restrict__ bxh, const float* __restrict__ bhh,
    const float* __restrict__ bh, f16* __restrict__ xp)
{
    __shared__ __align__(16) f16 As[64 * P1_AS];
    __shared__ __align__(16) f16 Bs[512 * P1_AS];

    const int t = threadIdx.x;
    const int wave = t >> 6, lane = t & 63;
    const size_t mbase = (size_t)blockIdx.x * 64;

    f32x4 acc[4][8];
#pragma unroll
    for (int i = 0; i < 4; i++)
#pragma unroll
        for (int j = 0; j < 8; j++) acc[i][j] = (f32x4){0.f, 0.f, 0.f, 0.f};

    const int r_st = t >> 2;          // 0..63
    const int koff = (t & 3) * 8;     // 0,8,16,24

    for (int k0 = 0; k0 < 512; k0 += 32) {
        __syncthreads();
        // stage A: 64 rows x 32 k (f32 -> f16)
        {
            const float* src = x + (mbase + r_st) * 512 + k0 + koff;
            float4 a0 = *(const float4*)src;
            float4 a1 = *(const float4*)(src + 4);
            f16x8 h;
            h[0] = (f16)a0.x; h[1] = (f16)a0.y; h[2] = (f16)a0.z; h[3] = (f16)a0.w;
            h[4] = (f16)a1.x; h[5] = (f16)a1.y; h[6] = (f16)a1.z; h[7] = (f16)a1.w;
            *(f16x8*)&As[r_st * P1_AS + koff] = h;
        }
        // stage B: 512 rows(n) x 32 k, 8 passes
#pragma unroll
        for (int i = 0; i < 8; i++) {
            int n = r_st + i * 64;
            const float* src = Wxh + (size_t)n * 512 + k0 + koff;
            float4 b0 = *(const float4*)src;
            float4 b1 = *(const float4*)(src + 4);
            f16x8 h;
            h[0] = (f16)b0.x; h[1] = (f16)b0.y; h[2] = (f16)b0.z; h[3] = (f16)b0.w;
            h[4] = (f16)b1.x; h[5] = (f16)b1.y; h[6] = (f16)b1.z; h[7] = (f16)b1.w;
            *(f16x8*)&Bs[n * P1_AS + koff] = h;
        }
        __syncthreads();

        // A frags: row = rt*16 + (lane&15), k = (lane>>4)*8 + j
        f16x8 af[4];
#pragma unroll
        for (int rt = 0; rt < 4; rt++)
            af[rt] = *(const f16x8*)&As[(rt * 16 + (lane & 15)) * P1_AS + (lane >> 4) * 8];
#pragma unroll
        for (int ct = 0; ct < 8; ct++) {
            f16x8 bf = *(const f16x8*)&Bs[((wave * 8 + ct) * 16 + (lane & 15)) * P1_AS + (lane >> 4) * 8];
#pragma unroll
            for (int rt = 0; rt < 4; rt++)
                acc[rt][ct] = __builtin_amdgcn_mfma_f32_16x16x32_f16(af[rt], bf, acc[rt][ct], 0, 0, 0);
        }
    }

    // epilogue: D col = lane&15, row = (lane>>4)*4 + r
#pragma unroll
    for (int ct = 0; ct < 8; ct++) {
        int n = wave * 128 + ct * 16 + (lane & 15);
        float bias = bxh[n] + bhh[n] + bh[n];
#pragma unroll
        for (int rt = 0; rt < 4; rt++) {
#pragma unroll
            for (int r = 0; r < 4; r++) {
                size_t m = mbase + rt * 16 + (lane >> 4) * 4 + r;
                xp[m * 512 + n] = (f16)(acc[rt][ct][r] + bias);
            }
        }
    }
}

// ---------------------------------------------------------------------------
// Phase 2: recurrence.  1 block (512 thr, 8 waves) per batch, 32 blocks.
//
// Evidence so far:
//   r0 (dist-1 float xp prefetch, 48 reg-frags + 16 kf LDS):   2447 us  [best]
//   r1 (asm barrier + raw-f16 dist-2 prefetch):                2781 us
//   r2 (syncthreads + raw-f16 dist-2 prefetch + 12 kf LDS):    2727 us
// -> raw-f16 dist-2 rotation cost ~+300; LDS-BW reduction ~neutral.
//    LDS *bandwidth* is NOT the bottleneck; per-kf exposed ds_read latency
//    (~80 cyc x 16 kf) is the prime suspect for the ~1500 cyc/step gap.
//
// Round 3: r0 step-loop structure restored (dist-1 float xv prefetch,
// __syncthreads), keep 52 reg-frags + 12 kf LDS, and EXPLICIT distance-1
// software pipelining of the av/bl ds_reads (issue kf+1's reads before
// kf's MFMAs; 8 extra VGPRs for the rotation buffers).
// ---------------------------------------------------------------------------
#define P2_LDS_BYTES (2 * HID * 2 + 8 * 12 * 512 * 2)  // h bufs + ldsB = 100352

__global__ __launch_bounds__(512, 2) void rnn_kernel(
    const float* __restrict__ Whh, const f16* __restrict__ xp,
    f16* __restrict__ hfin)
{
    extern __shared__ __align__(16) char smem[];
    f16* hbuf0 = (f16*)smem;                 // 512
    f16* hbuf1 = hbuf0 + HID;                // 512
    f16* ldsB  = hbuf1 + HID;                // [(wave*12 + j)*512 + lane*8], j=kf-4

    const int t = threadIdx.x;
    const int wave = t >> 6, lane = t & 63;
    const int b = blockIdx.x;

    const int c_in = lane & 15;              // fragment column
    const int k8   = (lane >> 4) * 8;        // fragment k base

    // ---- load W_hh fragments (one-time) ----
    // tiles nt = wave*4 + r, r=0..2 fully in reg; tile 3: kf 0..3 in reg,
    // kf 4..15 in LDS (fragment order).
    f16x8 wreg[52];                          // 52 frags -> 208 regs
#pragma unroll
    for (int r = 0; r < 3; r++) {
        const float* wrow = Whh + (size_t)((wave * 4 + r) * 16 + c_in) * 512;
#pragma unroll
        for (int kf = 0; kf < 16; kf++) {
            float4 w0 = *(const float4*)(wrow + kf * 32 + k8);
            float4 w1 = *(const float4*)(wrow + kf * 32 + k8 + 4);
            f16x8 h;
            h[0] = (f16)w0.x; h[1] = (f16)w0.y; h[2] = (f16)w0.z; h[3] = (f16)w0.w;
            h[4] = (f16)w1.x; h[5] = (f16)w1.y; h[6] = (f16)w1.z; h[7] = (f16)w1.w;
            wreg[r * 16 + kf] = h;
        }
    }
    {   // 4th tile
        const float* wrow = Whh + (size_t)((wave * 4 + 3) * 16 + c_in) * 512;
#pragma unroll
        for (int kf = 0; kf < 16; kf++) {
            float4 w0 = *(const float4*)(wrow + kf * 32 + k8);
            float4 w1 = *(const float4*)(wrow + kf * 32 + k8 + 4);
            f16x8 h;
            h[0] = (f16)w0.x; h[1] = (f16)w0.y; h[2] = (f16)w0.z; h[3] = (f16)w0.w;
            h[4] = (f16)w1.x; h[5] = (f16)w1.y; h[6] = (f16)w1.z; h[7] = (f16)w1.w;
            if (kf < 4)
                wreg[48 + kf] = h;
            else
                *(f16x8*)&ldsB[((size_t)wave * 12 + (kf - 4)) * 512 + lane * 8] = h;
        }
    }
    hbuf0[t & (HID - 1)] = (f16)0.f;         // h0 = 0 (512 threads cover 512)
    __syncthreads();

    const f16* xprow = xp + (size_t)b * SEQL * 512 + wave * 64 + lane;
    const int ldsb_base = wave * 12 * 512 + lane * 8;

    // xp prefetch: distance-1, float (r0 structure — measured best).
    float xv = (float)xprow[0];
    for (int s = 0; s < NSTEP; s++) {
        const f16* cur = (s & 1) ? hbuf1 : hbuf0;
        f16*       nxt = (s & 1) ? hbuf0 : hbuf1;
        int sn = (s + 1 < NSTEP) ? s + 1 : s;
        float xv_next = (float)xprow[(size_t)sn * 512];

        f32x4 a0 = (f32x4){0.f,0.f,0.f,0.f}, a1 = a0, a2 = a0, a3 = a0;

        // distance-1 pipelined ds_reads: kf+1's av/bl issue BEFORE kf's MFMAs
        f16x8 av_c = *(const f16x8*)&cur[k8];                       // kf 0
        f16x8 bl_c = *(const f16x8*)&ldsB[ldsb_base];               // frag for kf=4
        f16x8 av_n, bl_n;
#pragma unroll
        for (int kf = 0; kf < 16; kf++) {
            if (kf < 15)
                av_n = *(const f16x8*)&cur[(kf + 1) * 32 + k8];
            if (kf >= 4 && kf < 15)
                bl_n = *(const f16x8*)&ldsB[ldsb_base + (kf - 3) * 512];
            a0 = __builtin_amdgcn_mfma_f32_16x16x32_f16(av_c, wreg[kf],      a0, 0, 0, 0);
            a1 = __builtin_amdgcn_mfma_f32_16x16x32_f16(av_c, wreg[16 + kf], a1, 0, 0, 0);
            a2 = __builtin_amdgcn_mfma_f32_16x16x32_f16(av_c, wreg[32 + kf], a2, 0, 0, 0);
            if (kf < 4)
                a3 = __builtin_amdgcn_mfma_f32_16x16x32_f16(av_c, wreg[48 + kf], a3, 0, 0, 0);
            else
                a3 = __builtin_amdgcn_mfma_f32_16x16x32_f16(av_c, bl_c, a3, 0, 0, 0);
            if (kf < 15) av_c = av_n;
            if (kf >= 4 && kf < 15) bl_c = bl_n;
        }

        // lane l owns h_new[wave*64 + l]: tile = l>>4, col = l&15, any row (reg 0)
        int r = lane >> 4;
        float v = (r == 0) ? a0[0] : (r == 1) ? a1[0] : (r == 2) ? a2[0] : a3[0];
        v += xv;
        // tanh(v) = 1 - 2/(exp(2v)+1)   (saturates correctly, no NaN)
        float e = __expf(2.f * v);
        v = 1.f - 2.f / (e + 1.f);
        nxt[wave * 64 + lane] = (f16)v;
        xv = xv_next;
        __syncthreads();
    }
    // NSTEP even -> final h sits in hbuf0
    hfin[(size_t)b * 512 + t] = hbuf0[t & (HID - 1)];
}

// ---------------------------------------------------------------------------
// Phase 3: out[b][o] = sum_k h[b][k] * Wfc[o][k] + bfc[o]  (fp32 out)
// 32 blocks x 16 o-slice, 256 threads; h staged in padded LDS.
// ---------------------------------------------------------------------------
#define P3_HS 520  // padded stride (f16); 1040B is 16B-aligned

__global__ __launch_bounds__(256, 2) void fc_kernel(
    const f16* __restrict__ hfin, const float* __restrict__ Wfc,
    const float* __restrict__ bfc, float* __restrict__ out)
{
    __shared__ __align__(16) f16 hs[BATCH * P3_HS];
    const int t = threadIdx.x;
    // stage h (coalesced 2B loads, scattered padded LDS writes — one-time)
    for (int i = 0; i < 64; i++) {
        int e = i * 256 + t;                 // 0..16383
        hs[(e >> 9) * P3_HS + (e & 511)] = hfin[e];
    }
    __syncthreads();

    const int bidx = t & 31;
    const int oi = t >> 5;                   // 0..7
    const int o0 = blockIdx.x * 16;
    const int oA = o0 + oi, oB = o0 + oi + 8;
    const float* wA = Wfc + (size_t)oA * 512;
    const float* wB = Wfc + (size_t)oB * 512;

    float sA = 0.f, sB = 0.f;
#pragma unroll 4
    for (int kb = 0; kb < 64; kb++) {
        f16x8 hv = *(const f16x8*)&hs[bidx * P3_HS + kb * 8];
        float4 wa0 = *(const float4*)(wA + kb * 8);
        float4 wa1 = *(const float4*)(wA + kb * 8 + 4);
        float4 wb0 = *(const float4*)(wB + kb * 8);
        float4 wb1 = *(const float4*)(wB + kb * 8 + 4);
        float h0 = (float)hv[0], h1 = (float)hv[1], h2 = (float)hv[2], h3 = (float)hv[3];
        float h4 = (float)hv[4], h5 = (float)hv[5], h6 = (float)hv[6], h7 = (float)hv[7];
        sA += wa0.x*h0 + wa0.y*h1 + wa0.z*h2 + wa0.w*h3 + wa1.x*h4 + wa1.y*h5 + wa1.z*h6 + wa1.w*h7;
        sB += wb0.x*h0 + wb0.y*h1 + wb0.z*h2 + wb0.w*h3 + wb1.x*h4 + wb1.y*h5 + wb1.z*h6 + wb1.w*h7;
    }
    out[(size_t)bidx * 512 + oA] = sA + bfc[oA];
    out[(size_t)bidx * 512 + oB] = sB + bfc[oB];
}

// ---------------------------------------------------------------------------
extern "C" void kernel_launch(void* const* d_in, const int* in_sizes, int n_in,
                              void* d_out, int out_size, void* d_ws, size_t ws_size,
                              hipStream_t stream) {
    const float* x    = (const float*)d_in[0];
    const float* Wxh  = (const float*)d_in[1];
    const float* bxh  = (const float*)d_in[2];
    const float* Whh  = (const float*)d_in[3];
    const float* bhh  = (const float*)d_in[4];
    const float* bh   = (const float*)d_in[5];
    const float* Wfc  = (const float*)d_in[6];
    const float* bfc  = (const float*)d_in[7];
    float* outp = (float*)d_out;

    f16* xp   = (f16*)d_ws;                                   // 64 MiB
    f16* hfin = (f16*)((char*)d_ws + (size_t)BATCH * SEQL * 512 * 2);

    // allow 100 KiB dynamic LDS for the rnn kernel (idempotent, capture-safe)
    hipFuncSetAttribute((const void*)rnn_kernel,
                        hipFuncAttributeMaxDynamicSharedMemorySize, 160 * 1024);

    xproj_kernel<<<(BATCH * SEQL) / 64, 256, 0, stream>>>(x, Wxh, bxh, bhh, bh, xp);
    rnn_kernel<<<BATCH, 512, P2_LDS_BYTES, stream>>>(Whh, xp, hfin);
    fc_kernel<<<32, 256, 0, stream>>>(hfin, Wfc, bfc, outp);
}